// Round 1
// baseline (510.346 us; speedup 1.0000x reference)
//
#include <hip/hip_runtime.h>
#include <hip/hip_bf16.h>

// out[b][i][d] = sum_l x_i[b][l][d]
// B=512, D=128, L_i = in_sizes[i] / (B*D)  (64..512)
//
// One block per (b, i). Thread layout: c = tid&31 -> float4 column (32 x 16B
// = 128 floats), r = tid>>5 -> row group (8 rows in flight). Each thread
// accumulates rows r, r+8, r+16, ... A wave (64 lanes) covers two adjacent
// rows = 1024 contiguous bytes per global_load_dwordx4 -> fully coalesced.

struct SumCatArgs {
    const float* x[8];
    int L[8];
};

__global__ __launch_bounds__(256) void fuse_sum_cat_kernel(
    SumCatArgs args, float* __restrict__ out) {
    const int blk = blockIdx.x;
    const int i = blk & 7;   // tensor index (low bits: spreads ragged work)
    const int b = blk >> 3;  // batch index

    const int L = args.L[i];
    const float4* __restrict__ xr =
        (const float4*)(args.x[i] + (size_t)b * (size_t)L * 128);

    const int c = threadIdx.x & 31;  // float4 column 0..31
    const int r = threadIdx.x >> 5;  // row group 0..7

    float4 acc = make_float4(0.f, 0.f, 0.f, 0.f);
    for (int l = r; l < L; l += 8) {
        float4 v = xr[(size_t)l * 32 + c];
        acc.x += v.x; acc.y += v.y; acc.z += v.z; acc.w += v.w;
    }

    __shared__ float4 part[8][32];
    part[r][c] = acc;
    __syncthreads();

    if (threadIdx.x < 32) {
        float4 s = part[0][c];
#pragma unroll
        for (int k = 1; k < 8; ++k) {
            float4 v = part[k][c];
            s.x += v.x; s.y += v.y; s.z += v.z; s.w += v.w;
        }
        float4* orow = (float4*)(out + ((size_t)b * 8 + i) * 128);
        orow[c] = s;
    }
}

extern "C" void kernel_launch(void* const* d_in, const int* in_sizes, int n_in,
                              void* d_out, int out_size, void* d_ws, size_t ws_size,
                              hipStream_t stream) {
    (void)d_ws; (void)ws_size; (void)out_size;

    SumCatArgs args;
    for (int i = 0; i < 8; ++i) {
        args.x[i] = (const float*)d_in[i];
        args.L[i] = in_sizes[i] / (512 * 128);  // B*D = 65536
    }

    const int n_blocks = 512 * 8;  // one block per (batch, tensor)
    fuse_sum_cat_kernel<<<n_blocks, 256, 0, stream>>>(args, (float*)d_out);
}

// Round 2
// 507.730 us; speedup vs baseline: 1.0052x; 1.0052x over previous
//
#include <hip/hip_runtime.h>
#include <hip/hip_bf16.h>

// out[b][i][d] = sum_l x_i[b][l][d]
// B=512, D=128, L_i = in_sizes[i] / (B*D)  (64..512, all multiples of 64)
//
// One block per (b, i). Thread layout: c = tid&31 -> float4 column (32 x 16B
// = 128 floats), r = tid>>5 -> row group (8 rows in flight). Inner loop is
// manually unrolled 8x (rows r, r+8, ..., r+56) so each thread keeps 8
// independent float4 loads outstanding before the first s_waitcnt -> 8x the
// memory-level parallelism of the R0 version (which had VGPR_Count=16 and
// exactly 1 outstanding load per wave -> latency-bound at 3 TB/s).

struct SumCatArgs {
    const float* x[8];
    int L[8];
};

__global__ __launch_bounds__(256) void fuse_sum_cat_kernel(
    SumCatArgs args, float* __restrict__ out) {
    const int blk = blockIdx.x;
    const int i = blk & 7;   // tensor index (low bits: spreads ragged work)
    const int b = blk >> 3;  // batch index

    const int L = args.L[i];
    const float4* __restrict__ xr =
        (const float4*)(args.x[i] + (size_t)b * (size_t)L * 128);

    const int c = threadIdx.x & 31;  // float4 column 0..31
    const int r = threadIdx.x >> 5;  // row group 0..7

    float4 acc0 = make_float4(0.f, 0.f, 0.f, 0.f);
    float4 acc1 = make_float4(0.f, 0.f, 0.f, 0.f);

    // L is always a multiple of 64 -> each thread's row count (L/8) is a
    // multiple of 8 -> the 8-deep unrolled body has no remainder.
    for (int l = r; l < L; l += 64) {
        float4 v[8];
#pragma unroll
        for (int u = 0; u < 8; ++u) {
            v[u] = xr[(size_t)(l + u * 8) * 32 + c];
        }
#pragma unroll
        for (int u = 0; u < 8; u += 2) {
            acc0.x += v[u].x; acc0.y += v[u].y;
            acc0.z += v[u].z; acc0.w += v[u].w;
            acc1.x += v[u + 1].x; acc1.y += v[u + 1].y;
            acc1.z += v[u + 1].z; acc1.w += v[u + 1].w;
        }
    }
    float4 acc = make_float4(acc0.x + acc1.x, acc0.y + acc1.y,
                             acc0.z + acc1.z, acc0.w + acc1.w);

    __shared__ float4 part[8][32];
    part[r][c] = acc;
    __syncthreads();

    if (threadIdx.x < 32) {
        float4 s = part[0][c];
#pragma unroll
        for (int k = 1; k < 8; ++k) {
            float4 v = part[k][c];
            s.x += v.x; s.y += v.y; s.z += v.z; s.w += v.w;
        }
        float4* orow = (float4*)(out + ((size_t)b * 8 + i) * 128);
        orow[c] = s;
    }
}

extern "C" void kernel_launch(void* const* d_in, const int* in_sizes, int n_in,
                              void* d_out, int out_size, void* d_ws, size_t ws_size,
                              hipStream_t stream) {
    (void)d_ws; (void)ws_size; (void)out_size;

    SumCatArgs args;
    for (int i = 0; i < 8; ++i) {
        args.x[i] = (const float*)d_in[i];
        args.L[i] = in_sizes[i] / (512 * 128);  // B*D = 65536
    }

    const int n_blocks = 512 * 8;  // one block per (batch, tensor)
    fuse_sum_cat_kernel<<<n_blocks, 256, 0, stream>>>(args, (float*)d_out);
}